// Round 1
// baseline (235.516 us; speedup 1.0000x reference)
//
#include <hip/hip_runtime.h>

#define N_HALF 4096
#define D 64
#define M_TOT 8192
#define TILE 128
#define NT 64  // 8192 / 128 tiles per dimension

// Device-global scratch (reset every call by mmd_init -> deterministic).
__device__ double g_acc;
__device__ float g_ssq;
__device__ float g_colsum[D];
__device__ float g_coef[5];

__global__ void mmd_init() {
    int t = threadIdx.x;
    if (t == 0) { g_acc = 0.0; g_ssq = 0.f; }
    if (t < D) g_colsum[t] = 0.f;
}

// Pass 1: sum of squares and per-column sums over concat(source,target).
__global__ __launch_bounds__(256) void mmd_stats(const float* __restrict__ src,
                                                 const float* __restrict__ tgt) {
    __shared__ float cs[D];
    __shared__ float wsum[4];
    int t = threadIdx.x;
    if (t < D) cs[t] = 0.f;
    __syncthreads();
    float ssq = 0.f, cpart = 0.f;
    const int stride = 256 * 128;  // grid = 128 blocks
    for (int idx = blockIdx.x * 256 + t; idx < N_HALF * D; idx += stride) {
        float a = src[idx], b = tgt[idx];
        ssq += a * a + b * b;
        cpart += a + b;  // column = idx & 63 = t & 63 (strides are multiples of 64)
    }
    atomicAdd(&cs[t & (D - 1)], cpart);
#pragma unroll
    for (int off = 32; off; off >>= 1) ssq += __shfl_down(ssq, off, 64);
    if ((t & 63) == 0) wsum[t >> 6] = ssq;
    __syncthreads();
    if (t == 0) atomicAdd(&g_ssq, wsum[0] + wsum[1] + wsum[2] + wsum[3]);
    if (t < D) atomicAdd(&g_colsum[t], cs[t]);
}

// Pass 2: bandwidth (closed form for sum(L2)) and exp2 coefficients.
__global__ void mmd_finalize() {
    double s2 = 0.0;
    for (int c = 0; c < D; ++c) { double v = (double)g_colsum[c]; s2 += v * v; }
    const double M = (double)M_TOT;
    double sumL2 = 2.0 * M * (double)g_ssq - 2.0 * s2;
    double bw = sumL2 / (M * M - M);
    bw *= 0.25;  // / KERNEL_MUL^(KERNEL_NUM//2) = / 4
    const double log2e = 1.4426950408889634;
    for (int i = 0; i < 5; ++i)
        g_coef[i] = (float)(-log2e / (bw * (double)(1 << i)));
}

// Pass 3: tiled pairwise kernel sums. Upper-triangle tiles only (K symmetric).
// 128x128 pair tile, 256 threads, 8x8 micro-tile strided by 16, k split in 2
// halves of 32 staged in LDS with XOR float4-block swizzle.
__global__ __launch_bounds__(256) void mmd_main(const float* __restrict__ src,
                                                const float* __restrict__ tgt) {
    int bi = blockIdx.x & (NT - 1);
    int bj = blockIdx.x >> 6;
    if (bj < bi) return;  // symmetry: only upper triangle of tile grid

    __shared__ float As[TILE * 32];  // k-half tile, swizzled float4 blocks (8/row)
    __shared__ float Bs[TILE * 32];
    __shared__ float sqA[TILE];
    __shared__ float sqB[TILE];
    __shared__ float wred[4];

    const float* Ab = (bi < 32) ? src + (size_t)bi * TILE * D
                                : tgt + (size_t)(bi - 32) * TILE * D;
    const float* Bb = (bj < 32) ? src + (size_t)bj * TILE * D
                                : tgt + (size_t)(bj - 32) * TILE * D;
    float sgnscl = (((bi < 32) == (bj < 32)) ? 1.f : -1.f) * ((bi == bj) ? 1.f : 2.f);

    int t = threadIdx.x;

    // Row squared-norms straight from global (L2-resident).
    {
        const float* base = (t < 128) ? Ab : Bb;
        int r = t & 127;
        const float4* rp = (const float4*)(base + r * D);
        float s = 0.f;
#pragma unroll
        for (int b = 0; b < 16; ++b) {
            float4 v = rp[b];
            s += v.x * v.x + v.y * v.y + v.z * v.z + v.w * v.w;
        }
        if (t < 128) sqA[r] = s; else sqB[r] = s;
    }

    int tx = t & 15, ty = t >> 4;
    float acc[8][8] = {};

    for (int half = 0; half < 2; ++half) {
        __syncthreads();  // also covers sqA/sqB writes before epilogue reads
#pragma unroll
        for (int q = 0; q < 4; ++q) {
            int f = t + q * 256;  // 0..1023 float4 slots per operand
            int row = f >> 3, blk = f & 7;
            int p = blk ^ (row & 7);  // XOR swizzle (store side)
            ((float4*)As)[row * 8 + p] = ((const float4*)Ab)[row * 16 + half * 8 + blk];
            ((float4*)Bs)[row * 8 + p] = ((const float4*)Bb)[row * 16 + half * 8 + blk];
        }
        __syncthreads();
#pragma unroll
        for (int kb = 0; kb < 8; ++kb) {
            float4 a[8], b[8];
#pragma unroll
            for (int m = 0; m < 8; ++m) {
                int ia = ty + m * 16;
                a[m] = ((const float4*)As)[ia * 8 + (kb ^ (ia & 7))];  // XOR (read side)
                int jb = tx + m * 16;
                b[m] = ((const float4*)Bs)[jb * 8 + (kb ^ (jb & 7))];
            }
#pragma unroll
            for (int ii = 0; ii < 8; ++ii)
#pragma unroll
                for (int jj = 0; jj < 8; ++jj)
                    acc[ii][jj] += a[ii].x * b[jj].x + a[ii].y * b[jj].y +
                                   a[ii].z * b[jj].z + a[ii].w * b[jj].w;
        }
    }

    // Epilogue: L2 -> 5-bandwidth Gaussian kernel sum via hardware exp2.
    float g0 = g_coef[0], g1 = g_coef[1], g2 = g_coef[2], g3 = g_coef[3], g4 = g_coef[4];
    float part = 0.f;
#pragma unroll
    for (int ii = 0; ii < 8; ++ii) {
        float sa = sqA[ty + ii * 16];
#pragma unroll
        for (int jj = 0; jj < 8; ++jj) {
            float l2 = sa + sqB[tx + jj * 16] - 2.f * acc[ii][jj];
            part += __builtin_amdgcn_exp2f(l2 * g0) + __builtin_amdgcn_exp2f(l2 * g1) +
                    __builtin_amdgcn_exp2f(l2 * g2) + __builtin_amdgcn_exp2f(l2 * g3) +
                    __builtin_amdgcn_exp2f(l2 * g4);
        }
    }

#pragma unroll
    for (int off = 32; off; off >>= 1) part += __shfl_down(part, off, 64);
    if ((t & 63) == 0) wred[t >> 6] = part;
    __syncthreads();
    if (t == 0)
        atomicAdd(&g_acc, (double)(wred[0] + wred[1] + wred[2] + wred[3]) * (double)sgnscl);
}

__global__ void mmd_out(float* __restrict__ out) {
    // result = (sumXX + sumYY - sumXY - sumYX) / 4096^2
    out[0] = (float)(g_acc * (1.0 / 16777216.0));
}

extern "C" void kernel_launch(void* const* d_in, const int* in_sizes, int n_in,
                              void* d_out, int out_size, void* d_ws, size_t ws_size,
                              hipStream_t stream) {
    const float* src = (const float*)d_in[0];
    const float* tgt = (const float*)d_in[1];
    float* out = (float*)d_out;

    mmd_init<<<1, 128, 0, stream>>>();
    mmd_stats<<<128, 256, 0, stream>>>(src, tgt);
    mmd_finalize<<<1, 1, 0, stream>>>();
    mmd_main<<<NT * NT, 256, 0, stream>>>(src, tgt);
    mmd_out<<<1, 1, 0, stream>>>(out);
}

// Round 2
// 68.259 us; speedup vs baseline: 3.4503x; 3.4503x over previous
//
#include <hip/hip_runtime.h>

#define N_HALF 4096
#define D 64
#define M_TOT 8192
#define NT16 512   // 8192/16 row-tiles of 16
#define NB 32      // 8192/256 block-stripes

typedef short short8_t __attribute__((ext_vector_type(8)));
typedef float f32x4 __attribute__((ext_vector_type(4)));

// Device-global scratch (rewritten every call -> deterministic).
__device__ double g_acc;
__device__ float g_ssq;
__device__ float g_colsum[D];
__device__ float g_coef[5];
__device__ unsigned short Fhi[NT16 * 2 * 64 * 8];  // 1 MB: fragment-major bf16 hi
__device__ unsigned short Flo[NT16 * 2 * 64 * 8];  // 1 MB: bf16 lo (x - hi)
__device__ float g_norms[M_TOT];

static __device__ inline unsigned short f2bf(float x) {
    union { float f; unsigned u; } v; v.f = x;
    unsigned r = v.u + 0x7fff + ((v.u >> 16) & 1);  // RNE
    return (unsigned short)(r >> 16);
}
static __device__ inline float bf2f(unsigned short h) {
    union { unsigned u; float f; } v; v.u = ((unsigned)h) << 16;
    return v.f;
}

__global__ void mmd_init() {
    int t = threadIdx.x;
    if (t == 0) { g_acc = 0.0; g_ssq = 0.f; }
    if (t < D) g_colsum[t] = 0.f;
}

// Pass 1: sum of squares and per-column sums (for the closed-form bandwidth).
__global__ __launch_bounds__(256) void mmd_stats(const float* __restrict__ src,
                                                 const float* __restrict__ tgt) {
    __shared__ float cs[D];
    __shared__ float wsum[4];
    int t = threadIdx.x;
    if (t < D) cs[t] = 0.f;
    __syncthreads();
    float ssq = 0.f, cpart = 0.f;
    const int stride = 256 * 128;
    for (int idx = blockIdx.x * 256 + t; idx < N_HALF * D; idx += stride) {
        float a = src[idx], b = tgt[idx];
        ssq += a * a + b * b;
        cpart += a + b;
    }
    atomicAdd(&cs[t & (D - 1)], cpart);
#pragma unroll
    for (int off = 32; off; off >>= 1) ssq += __shfl_down(ssq, off, 64);
    if ((t & 63) == 0) wsum[t >> 6] = ssq;
    __syncthreads();
    if (t == 0) atomicAdd(&g_ssq, wsum[0] + wsum[1] + wsum[2] + wsum[3]);
    if (t < D) atomicAdd(&g_colsum[t], cs[t]);
}

// Pass 2: bandwidth via sum(L2) = 2*M*ssq - 2*||colsum||^2; exp2 coefficients.
__global__ void mmd_finalize() {
    double s2 = 0.0;
    for (int c = 0; c < D; ++c) { double v = (double)g_colsum[c]; s2 += v * v; }
    const double M = (double)M_TOT;
    double sumL2 = 2.0 * M * (double)g_ssq - 2.0 * s2;
    double bw = sumL2 / (M * M - M);
    bw *= 0.25;  // / KERNEL_MUL^(KERNEL_NUM//2)
    const double log2e = 1.4426950408889634;
    for (int i = 0; i < 5; ++i)
        g_coef[i] = (float)(-log2e / (bw * (double)(1 << i)));
}

// Pass 3a: split-bf16 convert into MFMA fragment-major layout.
// F[rt][s][lane][e] = X[rt*16 + (lane&15)][s*32 + (lane>>4)*8 + e]
// (any per-MFMA k-bijection works: both operands use the same layout, and
//  dot products are permutation-invariant in k)
__global__ __launch_bounds__(256) void mmd_convert(const float* __restrict__ src,
                                                   const float* __restrict__ tgt) {
    int tid = blockIdx.x * 256 + threadIdx.x;  // 65536 threads
    int l = tid & 63;
    int rs = tid >> 6;
    int s = rs & 1, rt = rs >> 1;
    int row = rt * 16 + (l & 15);
    int k0 = s * 32 + (l >> 4) * 8;
    const float* X = (row < N_HALF) ? src + (size_t)row * D : tgt + (size_t)(row - N_HALF) * D;
    float4 v0 = ((const float4*)(X + k0))[0];
    float4 v1 = ((const float4*)(X + k0))[1];
    float vs[8] = {v0.x, v0.y, v0.z, v0.w, v1.x, v1.y, v1.z, v1.w};
    unsigned short hi[8], lo[8];
#pragma unroll
    for (int e = 0; e < 8; ++e) {
        hi[e] = f2bf(vs[e]);
        lo[e] = f2bf(vs[e] - bf2f(hi[e]));
    }
    typedef unsigned short us8 __attribute__((ext_vector_type(8)));
    us8 h, o;
#pragma unroll
    for (int e = 0; e < 8; ++e) { h[e] = hi[e]; o[e] = lo[e]; }
    ((us8*)Fhi)[tid] = h;
    ((us8*)Flo)[tid] = o;
}

// Pass 3b: exact fp32 row norms.
__global__ __launch_bounds__(256) void mmd_norms(const float* __restrict__ src,
                                                 const float* __restrict__ tgt) {
    int t = blockIdx.x * 256 + threadIdx.x;  // 131072 threads
    int row = t >> 4, q = t & 15;
    const float* X = (row < N_HALF) ? src + (size_t)row * D : tgt + (size_t)(row - N_HALF) * D;
    float4 v = ((const float4*)X)[q];
    float s = v.x * v.x + v.y * v.y + v.z * v.z + v.w * v.w;
    s += __shfl_down(s, 8, 16);
    s += __shfl_down(s, 4, 16);
    s += __shfl_down(s, 2, 16);
    s += __shfl_down(s, 1, 16);
    if (q == 0) g_norms[row] = s;
}

// Pass 4: 256x256 output tiles, upper triangle, 8 waves/block.
// Per wave: 128x64 output = 8x4 MFMA tiles of 16x16, K=64 in 2 steps of 32,
// 3 MFMAs per tile per k-step (hihi + hilo + lohi). Operands direct from L2.
__global__ __launch_bounds__(512, 2) void mmd_main() {
    int bi = blockIdx.x & (NB - 1);
    int bj = blockIdx.x >> 5;
    if (bj < bi) return;

    __shared__ float nsA[256], nsB[256];
    __shared__ float wred[8];
    int t = threadIdx.x;
    if (t < 256) nsA[t] = g_norms[bi * 256 + t];
    else nsB[t - 256] = g_norms[bj * 256 + (t - 256)];
    __syncthreads();

    int w = t >> 6, l = t & 63;
    int wr = w >> 2, wc = w & 3;  // 2x4 wave grid: wave tile 128 rows x 64 cols

    const short8_t* FH = (const short8_t*)Fhi;
    const short8_t* FL = (const short8_t*)Flo;

    f32x4 acc[8][4] = {};
#pragma unroll
    for (int s = 0; s < 2; ++s) {
        short8_t bh[4], bl[4];
#pragma unroll
        for (int n = 0; n < 4; ++n) {
            int idx = (((bj * 16 + wc * 4 + n) * 2 + s) << 6) + l;
            bh[n] = FH[idx]; bl[n] = FL[idx];
        }
#pragma unroll
        for (int m = 0; m < 8; ++m) {
            int idx = (((bi * 16 + wr * 8 + m) * 2 + s) << 6) + l;
            short8_t ah = FH[idx], al = FL[idx];
#pragma unroll
            for (int n = 0; n < 4; ++n) {
                acc[m][n] = __builtin_amdgcn_mfma_f32_16x16x32_bf16(al, bh[n], acc[m][n], 0, 0, 0);
                acc[m][n] = __builtin_amdgcn_mfma_f32_16x16x32_bf16(ah, bl[n], acc[m][n], 0, 0, 0);
                acc[m][n] = __builtin_amdgcn_mfma_f32_16x16x32_bf16(ah, bh[n], acc[m][n], 0, 0, 0);
            }
        }
    }

    // Epilogue: l2 -> 5 bandwidths via ONE exp2 + 4 squarings:
    // K_i = exp2(l2*g0*2^-i); K4 = exp2(t0/16), K3 = K4^2, ... K0 = K1^2.
    float g0_16 = g_coef[0] * 0.0625f;
    float nbv[4];
#pragma unroll
    for (int n = 0; n < 4; ++n) nbv[n] = nsB[wc * 64 + n * 16 + (l & 15)];

    float part = 0.f;
#pragma unroll
    for (int m = 0; m < 8; ++m) {
        float nav[4];
#pragma unroll
        for (int r = 0; r < 4; ++r) nav[r] = nsA[wr * 128 + m * 16 + (l >> 4) * 4 + r];
#pragma unroll
        for (int n = 0; n < 4; ++n) {
#pragma unroll
            for (int r = 0; r < 4; ++r) {
                float l2 = nav[r] + nbv[n] - 2.f * acc[m][n][r];
                float k4 = __builtin_amdgcn_exp2f(l2 * g0_16);
                float k3 = k4 * k4;
                float k2 = k3 * k3;
                float k1 = k2 * k2;
                float k0 = k1 * k1;
                part += k4 + k3 + k2 + k1 + k0;
            }
        }
    }

#pragma unroll
    for (int off = 32; off; off >>= 1) part += __shfl_down(part, off, 64);
    if (l == 0) wred[w] = part;
    __syncthreads();
    if (t == 0) {
        float tot = 0.f;
#pragma unroll
        for (int q = 0; q < 8; ++q) tot += wred[q];
        float sgn = ((bi < 16) == (bj < 16)) ? 1.f : -1.f;
        float scl = (bi == bj) ? 1.f : 2.f;
        atomicAdd(&g_acc, (double)tot * (double)(sgn * scl));
    }
}

__global__ void mmd_out(float* __restrict__ out) {
    out[0] = (float)(g_acc * (1.0 / 16777216.0));  // / 4096^2
}

extern "C" void kernel_launch(void* const* d_in, const int* in_sizes, int n_in,
                              void* d_out, int out_size, void* d_ws, size_t ws_size,
                              hipStream_t stream) {
    const float* src = (const float*)d_in[0];
    const float* tgt = (const float*)d_in[1];
    float* out = (float*)d_out;

    mmd_init<<<1, 128, 0, stream>>>();
    mmd_stats<<<128, 256, 0, stream>>>(src, tgt);
    mmd_finalize<<<1, 1, 0, stream>>>();
    mmd_convert<<<256, 256, 0, stream>>>(src, tgt);
    mmd_norms<<<512, 256, 0, stream>>>(src, tgt);
    mmd_main<<<NB * NB, 512, 0, stream>>>();
    mmd_out<<<1, 1, 0, stream>>>(out);
}

// Round 3
// 61.731 us; speedup vs baseline: 3.8152x; 1.1057x over previous
//
#include <hip/hip_runtime.h>
#include <math.h>

#define N_HALF 4096
#define D 64
#define M_TOT 8192
#define NTB 64      // 8192/128 tiles per dimension
#define NPAIR 2080  // NTB*(NTB+1)/2 upper-triangle blocks

typedef short short8_t __attribute__((ext_vector_type(8)));
typedef unsigned short us8 __attribute__((ext_vector_type(8)));
typedef float f32x4 __attribute__((ext_vector_type(4)));

// Device-global scratch (fully rewritten every call -> deterministic).
__device__ double g_acc;
__device__ float g_ssq;
__device__ float g_colsum[D];
__device__ unsigned short Fhi[M_TOT * D];  // 1 MB fragment-major bf16 hi
__device__ unsigned short Flo[M_TOT * D];  // 1 MB bf16 lo residue
__device__ float g_norms[M_TOT];

static __device__ inline unsigned short f2bf(float x) {
    union { float f; unsigned u; } v; v.f = x;
    unsigned r = v.u + 0x7fff + ((v.u >> 16) & 1);  // RNE
    return (unsigned short)(r >> 16);
}
static __device__ inline float bf2f(unsigned short h) {
    union { unsigned u; float f; } v; v.u = ((unsigned)h) << 16;
    return v.f;
}

#define GLOAD16(gp, lp)                                        \
    __builtin_amdgcn_global_load_lds(                          \
        (const __attribute__((address_space(1))) void*)(gp),   \
        (__attribute__((address_space(3))) void*)(lp), 16, 0, 0)

__global__ void mmd_init() {
    int t = threadIdx.x;
    if (t == 0) { g_acc = 0.0; g_ssq = 0.f; }
    if (t < D) g_colsum[t] = 0.f;
}

// Fused: split-bf16 convert to fragment-major + row norms + ssq + colsums.
// F[rt][s][lane][e] = X[rt*16 + (lane&15)][s*32 + (lane>>4)*8 + e]
__global__ __launch_bounds__(256) void mmd_prep(const float* __restrict__ src,
                                                const float* __restrict__ tgt) {
    __shared__ float cs[D];
    __shared__ float hn[4][16];
    int t = threadIdx.x;
    if (t < D) cs[t] = 0.f;
    int tid = blockIdx.x * 256 + t;  // 65536 threads total
    int l = tid & 63;
    int rs = tid >> 6;
    int s = rs & 1, rt = rs >> 1;
    int row = rt * 16 + (l & 15);
    int k0 = s * 32 + (l >> 4) * 8;
    const float* X = (row < N_HALF) ? src + (size_t)row * D
                                    : tgt + (size_t)(row - N_HALF) * D;
    float4 v0 = ((const float4*)(X + k0))[0];
    float4 v1 = ((const float4*)(X + k0))[1];
    float vs[8] = {v0.x, v0.y, v0.z, v0.w, v1.x, v1.y, v1.z, v1.w};
    us8 h, o;
    float p = 0.f;
#pragma unroll
    for (int e = 0; e < 8; ++e) {
        unsigned short hi = f2bf(vs[e]);
        h[e] = hi;
        o[e] = f2bf(vs[e] - bf2f(hi));
        p += vs[e] * vs[e];
    }
    ((us8*)Fhi)[tid] = h;
    ((us8*)Flo)[tid] = o;
    __syncthreads();  // cs zeroed
#pragma unroll
    for (int e = 0; e < 8; ++e) atomicAdd(&cs[k0 + e], vs[e]);
    // lanes l, l+16, l+32, l+48 share (row, s-half)
    p += __shfl_down(p, 32, 64);
    p += __shfl_down(p, 16, 64);
    int w = t >> 6;  // wave w covers (rt = blk*2 + (w>>1), s = w&1)
    if (l < 16) hn[w][l] = p;
    __syncthreads();
    if (t < 64) {  // whole wave 0 active (shuffle-safe)
        float nr = 0.f;
        int tile = t >> 4, r = t & 15;
        if (t < 32) {
            nr = hn[tile * 2][r] + hn[tile * 2 + 1][r];
            g_norms[(blockIdx.x * 2 + tile) * 16 + r] = nr;
        }
        nr += __shfl_down(nr, 32, 64);
        nr += __shfl_down(nr, 16, 64);
        nr += __shfl_down(nr, 8, 64);
        nr += __shfl_down(nr, 4, 64);
        nr += __shfl_down(nr, 2, 64);
        nr += __shfl_down(nr, 1, 64);
        if (t == 0) atomicAdd(&g_ssq, nr);
    }
    if (t < D) atomicAdd(&g_colsum[t], cs[t]);
}

// Main: 128x128 output tiles over the exact upper triangle (2080 blocks).
// LDS-staged fragments (A hi+lo, B hi), 4 waves of 64x64, 2 MFMAs per
// 16x16 tile per k-step (hihi + loA*hiB; the missing hiA*loB term cancels
// to first order under the symmetric pair sum).
__global__ __launch_bounds__(256, 3) void mmd_main() {
    __shared__ unsigned short sAhi[8192], sAlo[8192], sBhi[8192];
    __shared__ float sred[4];
    __shared__ float sG0;

    int id = blockIdx.x;
    // decode id -> (bi, bj), bi <= bj; S(b) = 64b - b(b-1)/2
    int bi = (int)(64.5 - sqrt(4160.25 - 2.0 * (double)id));
    while ((64 * (bi + 1) - ((bi + 1) * bi) / 2) <= id) ++bi;
    while ((64 * bi - (bi * (bi - 1)) / 2) > id) --bi;
    int bj = bi + (id - (64 * bi - (bi * (bi - 1)) / 2));

    int t = threadIdx.x;
    {  // stage 3 x 16KB linear copies via async global->LDS
        const char* aHi = (const char*)Fhi + (size_t)bi * 16384;
        const char* aLo = (const char*)Flo + (size_t)bi * 16384;
        const char* bHi = (const char*)Fhi + (size_t)bj * 16384;
        int off = t * 16;
#pragma unroll
        for (int q = 0; q < 4; ++q) {
            GLOAD16(aHi + off, (char*)sAhi + off);
            GLOAD16(aLo + off, (char*)sAlo + off);
            GLOAD16(bHi + off, (char*)sBhi + off);
            off += 4096;
        }
    }
    if (t == 0) {  // bandwidth -> base exp2 coefficient (per-block, cheap)
        double s2 = 0.0;
        for (int c = 0; c < D; ++c) { double v = (double)g_colsum[c]; s2 += v * v; }
        const double M = (double)M_TOT;
        double sumL2 = 2.0 * M * (double)g_ssq - 2.0 * s2;
        double bw = sumL2 / (M * M - M) * 0.25;
        sG0 = (float)(-1.4426950408889634 / bw / 16.0);
    }
    __syncthreads();

    int w = t >> 6, l = t & 63;
    int wr = w >> 1, wc = w & 1;  // 2x2 wave grid, 64x64 per wave

    const short8_t* SA_hi = (const short8_t*)sAhi;
    const short8_t* SA_lo = (const short8_t*)sAlo;
    const short8_t* SB_hi = (const short8_t*)sBhi;

    f32x4 acc[4][4] = {};
#pragma unroll
    for (int s = 0; s < 2; ++s) {
        short8_t bh[4];
#pragma unroll
        for (int n = 0; n < 4; ++n)
            bh[n] = SB_hi[(((wc * 4 + n) * 2 + s) << 6) + l];
#pragma unroll
        for (int m = 0; m < 4; ++m) {
            int fi = (((wr * 4 + m) * 2 + s) << 6) + l;
            short8_t ah = SA_hi[fi], al = SA_lo[fi];
#pragma unroll
            for (int n = 0; n < 4; ++n) {
                acc[m][n] = __builtin_amdgcn_mfma_f32_16x16x32_bf16(al, bh[n], acc[m][n], 0, 0, 0);
                acc[m][n] = __builtin_amdgcn_mfma_f32_16x16x32_bf16(ah, bh[n], acc[m][n], 0, 0, 0);
            }
        }
    }

    // Epilogue: l2 -> 5 bandwidths via 1 exp2 + 4 squarings.
    float g0 = sG0;
    float c2 = -2.f * g0;
    float nas[4][4];
#pragma unroll
    for (int m = 0; m < 4; ++m) {
        float4 v = *(const float4*)&g_norms[bi * 128 + wr * 64 + m * 16 + (l >> 4) * 4];
        nas[m][0] = v.x * g0; nas[m][1] = v.y * g0;
        nas[m][2] = v.z * g0; nas[m][3] = v.w * g0;
    }
    float nbv[4];
#pragma unroll
    for (int n = 0; n < 4; ++n)
        nbv[n] = g_norms[bj * 128 + wc * 64 + n * 16 + (l & 15)] * g0;

    float part = 0.f;
#pragma unroll
    for (int m = 0; m < 4; ++m)
#pragma unroll
        for (int n = 0; n < 4; ++n)
#pragma unroll
            for (int r = 0; r < 4; ++r) {
                float t0 = fmaf(acc[m][n][r], c2, nas[m][r] + nbv[n]);
                float k4 = __builtin_amdgcn_exp2f(t0);
                float k3 = k4 * k4;
                float k2 = k3 * k3;
                float k1 = k2 * k2;
                float k0 = k1 * k1;
                part += (k4 + k3) + (k2 + k1) + k0;
            }

#pragma unroll
    for (int off = 32; off; off >>= 1) part += __shfl_down(part, off, 64);
    if (l == 0) sred[w] = part;
    __syncthreads();
    if (t == 0) {
        float tot = sred[0] + sred[1] + sred[2] + sred[3];
        float sgn = ((bi < 32) == (bj < 32)) ? 1.f : -1.f;
        float scl = (bi == bj) ? 1.f : 2.f;
        atomicAdd(&g_acc, (double)tot * (double)(sgn * scl));
    }
}

__global__ void mmd_out(float* __restrict__ out) {
    out[0] = (float)(g_acc * (1.0 / 16777216.0));  // / 4096^2
}

extern "C" void kernel_launch(void* const* d_in, const int* in_sizes, int n_in,
                              void* d_out, int out_size, void* d_ws, size_t ws_size,
                              hipStream_t stream) {
    const float* src = (const float*)d_in[0];
    const float* tgt = (const float*)d_in[1];
    float* out = (float*)d_out;

    mmd_init<<<1, 64, 0, stream>>>();
    mmd_prep<<<256, 256, 0, stream>>>(src, tgt);
    mmd_main<<<NPAIR, 256, 0, stream>>>();
    mmd_out<<<1, 1, 0, stream>>>(out);
}

// Round 4
// 46.676 us; speedup vs baseline: 5.0458x; 1.3225x over previous
//
#include <hip/hip_runtime.h>
#include <math.h>

#define N_HALF 4096
#define D 64
#define M_TOT 8192
#define NTB 64      // 8192/128 tiles per dimension
#define NPAIR 2080  // NTB*(NTB+1)/2 upper-triangle blocks

typedef short short8_t __attribute__((ext_vector_type(8)));
typedef unsigned short us8 __attribute__((ext_vector_type(8)));
typedef float f32x4 __attribute__((ext_vector_type(4)));

// Device-global scratch (fully rewritten every call -> deterministic).
__device__ float g_ssq;
__device__ float g_colsum[D];
__device__ float g_g0;
__device__ unsigned short Fhi[M_TOT * D];  // 1 MB fragment-major bf16 hi
__device__ unsigned short Flo[M_TOT * D];  // 1 MB bf16 lo residue
__device__ float g_norms[M_TOT];
__device__ double g_part[NPAIR];           // per-block signed partial sums

static __device__ inline unsigned short f2bf(float x) {
    union { float f; unsigned u; } v; v.f = x;
    unsigned r = v.u + 0x7fff + ((v.u >> 16) & 1);  // RNE
    return (unsigned short)(r >> 16);
}
static __device__ inline float bf2f(unsigned short h) {
    union { unsigned u; float f; } v; v.u = ((unsigned)h) << 16;
    return v.f;
}

__global__ void mmd_init() {
    int t = threadIdx.x;
    if (t == 0) g_ssq = 0.f;
    if (t < D) g_colsum[t] = 0.f;
}

// Fused: split-bf16 convert to fragment-major + row norms + ssq + colsums.
// F[rt][s][lane][e] = X[rt*16 + (lane&15)][s*32 + (lane>>4)*8 + e]
__global__ __launch_bounds__(256) void mmd_prep(const float* __restrict__ src,
                                                const float* __restrict__ tgt) {
    __shared__ float cs[D];
    __shared__ float hn[4][16];
    int t = threadIdx.x;
    if (t < D) cs[t] = 0.f;
    int tid = blockIdx.x * 256 + t;  // 65536 threads total
    int l = tid & 63;
    int rs = tid >> 6;
    int s = rs & 1, rt = rs >> 1;
    int row = rt * 16 + (l & 15);
    int k0 = s * 32 + (l >> 4) * 8;
    const float* X = (row < N_HALF) ? src + (size_t)row * D
                                    : tgt + (size_t)(row - N_HALF) * D;
    float4 v0 = ((const float4*)(X + k0))[0];
    float4 v1 = ((const float4*)(X + k0))[1];
    float vs[8] = {v0.x, v0.y, v0.z, v0.w, v1.x, v1.y, v1.z, v1.w};
    us8 h, o;
    float p = 0.f;
#pragma unroll
    for (int e = 0; e < 8; ++e) {
        unsigned short hi = f2bf(vs[e]);
        h[e] = hi;
        o[e] = f2bf(vs[e] - bf2f(hi));
        p += vs[e] * vs[e];
    }
    ((us8*)Fhi)[tid] = h;
    ((us8*)Flo)[tid] = o;
    __syncthreads();  // cs zeroed
#pragma unroll
    for (int e = 0; e < 8; ++e) atomicAdd(&cs[k0 + e], vs[e]);
    // lanes l, l+16, l+32, l+48 share (row, s-half)
    p += __shfl_down(p, 32, 64);
    p += __shfl_down(p, 16, 64);
    int w = t >> 6;  // wave w covers (rt = blk*2 + (w>>1), s = w&1)
    if (l < 16) hn[w][l] = p;
    __syncthreads();
    if (t < 64) {  // whole wave 0 active (shuffle-safe)
        float nr = 0.f;
        int tile = t >> 4, r = t & 15;
        if (t < 32) {
            nr = hn[tile * 2][r] + hn[tile * 2 + 1][r];
            g_norms[(blockIdx.x * 2 + tile) * 16 + r] = nr;
        }
        nr += __shfl_down(nr, 32, 64);
        nr += __shfl_down(nr, 16, 64);
        nr += __shfl_down(nr, 8, 64);
        nr += __shfl_down(nr, 4, 64);
        nr += __shfl_down(nr, 2, 64);
        nr += __shfl_down(nr, 1, 64);
        if (t == 0) atomicAdd(&g_ssq, nr);
    }
    if (t < D) atomicAdd(&g_colsum[t], cs[t]);
}

// Bandwidth via sum(L2) = 2*M*ssq - 2*||colsum||^2; base exp2 coefficient.
__global__ void mmd_finalize() {
    double s2 = 0.0;
    for (int c = 0; c < D; ++c) { double v = (double)g_colsum[c]; s2 += v * v; }
    const double M = (double)M_TOT;
    double sumL2 = 2.0 * M * (double)g_ssq - 2.0 * s2;
    double bw = sumL2 / (M * M - M) * 0.25;  // / KERNEL_MUL^(KERNEL_NUM//2)
    g_g0 = (float)(-1.4426950408889634 / bw / 16.0);
}

// Main: 128x128 output tiles over the exact upper triangle (2080 blocks).
// No LDS staging, no atomics: each wave loads its 24 fragments (16B each)
// straight from L2 with full memory-level parallelism, runs 64 MFMAs
// (hihi + loA*hiB; the hiA*loB term cancels under the symmetric pair sum),
// then the exp epilogue. One barrier for the block reduce; partial sums go
// to g_part (reduced in mmd_out) -- no same-address atomic serialization.
__global__ __launch_bounds__(256, 2) void mmd_main() {
    __shared__ float sred[4];
    int id = blockIdx.x;
    // decode id -> (bi, bj), bi <= bj; S(b) = 64b - b(b-1)/2
    int bi = (int)(64.5f - sqrtf(4160.25f - 2.0f * (float)id));
    while ((64 * (bi + 1) - ((bi + 1) * bi) / 2) <= id) ++bi;
    while ((64 * bi - (bi * (bi - 1)) / 2) > id) --bi;
    int bj = bi + (id - (64 * bi - (bi * (bi - 1)) / 2));

    int t = threadIdx.x, w = t >> 6, l = t & 63;
    int wr = w >> 1, wc = w & 1;  // 2x2 wave grid, 64x64 per wave

    const short8_t* FH = (const short8_t*)Fhi;
    const short8_t* FL = (const short8_t*)Flo;

    short8_t ah[2][4], al[2][4], bh[2][4];
#pragma unroll
    for (int s = 0; s < 2; ++s)
#pragma unroll
        for (int n = 0; n < 4; ++n)
            bh[s][n] = FH[((bj * 8 + wc * 4 + n) * 2 + s) * 64 + l];
#pragma unroll
    for (int s = 0; s < 2; ++s)
#pragma unroll
        for (int m = 0; m < 4; ++m) {
            int fi = ((bi * 8 + wr * 4 + m) * 2 + s) * 64 + l;
            ah[s][m] = FH[fi];
            al[s][m] = FL[fi];
        }

    f32x4 acc[4][4] = {};
#pragma unroll
    for (int s = 0; s < 2; ++s)
#pragma unroll
        for (int m = 0; m < 4; ++m)
#pragma unroll
            for (int n = 0; n < 4; ++n) {
                acc[m][n] = __builtin_amdgcn_mfma_f32_16x16x32_bf16(al[s][m], bh[s][n], acc[m][n], 0, 0, 0);
                acc[m][n] = __builtin_amdgcn_mfma_f32_16x16x32_bf16(ah[s][m], bh[s][n], acc[m][n], 0, 0, 0);
            }

    // Epilogue: l2 -> 5 bandwidths via 1 exp2 + 4 squarings.
    float g0 = g_g0;
    float c2 = -2.f * g0;
    float nas[4][4];
#pragma unroll
    for (int m = 0; m < 4; ++m) {
        float4 v = *(const float4*)&g_norms[bi * 128 + wr * 64 + m * 16 + (l >> 4) * 4];
        nas[m][0] = v.x * g0; nas[m][1] = v.y * g0;
        nas[m][2] = v.z * g0; nas[m][3] = v.w * g0;
    }
    float nbv[4];
#pragma unroll
    for (int n = 0; n < 4; ++n)
        nbv[n] = g_norms[bj * 128 + wc * 64 + n * 16 + (l & 15)] * g0;

    float part = 0.f;
#pragma unroll
    for (int m = 0; m < 4; ++m)
#pragma unroll
        for (int n = 0; n < 4; ++n)
#pragma unroll
            for (int r = 0; r < 4; ++r) {
                float t0 = fmaf(acc[m][n][r], c2, nas[m][r] + nbv[n]);
                float k4 = __builtin_amdgcn_exp2f(t0);
                float k3 = k4 * k4;
                float k2 = k3 * k3;
                float k1 = k2 * k2;
                float k0 = k1 * k1;
                part += (k4 + k3) + (k2 + k1) + k0;
            }

#pragma unroll
    for (int off = 32; off; off >>= 1) part += __shfl_down(part, off, 64);
    if (l == 0) sred[w] = part;
    __syncthreads();
    if (t == 0) {
        float tot = sred[0] + sred[1] + sred[2] + sred[3];
        float sgn = ((bi < 32) == (bj < 32)) ? 1.f : -1.f;
        float scl = (bi == bj) ? 1.f : 2.f;
        g_part[id] = (double)tot * (double)(sgn * scl);
    }
}

// Deterministic tree reduce of the 2080 per-block doubles.
__global__ __launch_bounds__(256) void mmd_out(float* __restrict__ out) {
    __shared__ double wred[4];
    int t = threadIdx.x;
    double s = 0.0;
    for (int i = t; i < NPAIR; i += 256) s += g_part[i];
#pragma unroll
    for (int off = 32; off; off >>= 1) s += __shfl_down(s, off, 64);
    if ((t & 63) == 0) wred[t >> 6] = s;
    __syncthreads();
    if (t == 0)
        out[0] = (float)((wred[0] + wred[1] + wred[2] + wred[3]) * (1.0 / 16777216.0));
}

extern "C" void kernel_launch(void* const* d_in, const int* in_sizes, int n_in,
                              void* d_out, int out_size, void* d_ws, size_t ws_size,
                              hipStream_t stream) {
    const float* src = (const float*)d_in[0];
    const float* tgt = (const float*)d_in[1];
    float* out = (float*)d_out;

    mmd_init<<<1, 64, 0, stream>>>();
    mmd_prep<<<256, 256, 0, stream>>>(src, tgt);
    mmd_finalize<<<1, 1, 0, stream>>>();
    mmd_main<<<NPAIR, 256, 0, stream>>>();
    mmd_out<<<1, 256, 0, stream>>>(out);
}